// Round 5
// baseline (1080.956 us; speedup 1.0000x reference)
//
#include <hip/hip_runtime.h>
#include <cstdint>

typedef _Float16 f16x2 __attribute__((ext_vector_type(2)));

#define L2E 1.44269504f

// Activations with log2(e) pre-folded into weights/biases:
// sig2(y) = 1/(1+2^-y)  (y = x*log2e already)
__device__ __forceinline__ float sig2(float y) {
  return __builtin_amdgcn_rcpf(1.f + exp2f(-y));
}
// tanh for runtime (unscaled) cell state c
__device__ __forceinline__ float tanhc(float c) {
  return fmaf(2.f, __builtin_amdgcn_rcpf(1.f + exp2f(c * (-2.f * L2E))), -1.f);
}
__device__ __forceinline__ int packf16(float a, float b) {
  f16x2 p; p.x = (_Float16)a; p.y = (_Float16)b;
  return __builtin_bit_cast(int, p);
}
__device__ __forceinline__ float dot2(int w, int h, float acc) {
  return __builtin_amdgcn_fdot2(__builtin_bit_cast(f16x2, w),
                                __builtin_bit_cast(f16x2, h), acc, false);
}
// Pair-lane permute via DPP quad_perm (lane ^ 1): ~4 cyc VALU.
template <int CTRL>
__device__ __forceinline__ float qp(float v) {
  return __int_as_float(__builtin_amdgcn_update_dpp(
      0, __float_as_int(v), CTRL, 0xF, 0xF, true));
}
#define QP_X1 0xB1  // quad_perm [1,0,3,2]  (lane ^ 1)

// ---------------------------------------------------------------------------
// R5: TWO SEQUENCES PER BLOCK (128 blocks x 512 threads). Threads 0-255 run
// seq 2b, threads 256-511 run seq 2b+1 -> 2 waves/SIMD, one from EACH
// independent recurrence. R4 accounting: step = ~1400 cyc but only ~360-400
// cyc of real VALU issue -> ~1000 cyc of exposed latency (LDS round-trip,
// act serial chain, barrier) that a single wave/SIMD cannot hide. The
// partner wave's issue fills those stalls; the shared per-step barrier
// lock-steps both chains but both do identical work so skew is small.
// Registers: 2 waves/SIMD -> 256 unified regs/wave, the ~190 live values
// fit. Everything inside a step is byte-identical to R4.
// ---------------------------------------------------------------------------
__global__ __launch_bounds__(512, 1) void fused_kernel(
    const float* __restrict__ x, const float* __restrict__ Wih1,
    const float* __restrict__ Whh1, const float* __restrict__ bih1,
    const float* __restrict__ bhh1, const float* __restrict__ Wih2,
    const float* __restrict__ Whh2, const float* __restrict__ bih2,
    const float* __restrict__ bhh2, const float* __restrict__ Wd1,
    const float* __restrict__ bd1, const float* __restrict__ Wd2,
    const float* __restrict__ bd2, float* __restrict__ out) {
  __shared__ __align__(16) int4 sX2[2][1026];        // h1 seqs (33 KB) + pad
  __shared__ __align__(16) _Float16 sH2[2][2][128];  // per-seq dbuf h

  const int b = blockIdx.x;
  const int t = threadIdx.x;

  // ======================== Phase 1: lstm1 ========================
  {
    // Block-uniform weights, log2e-folded (gate order i,f,g,o; g rows x2).
    int whh2[128];
#pragma unroll
    for (int r = 0; r < 32; ++r) {
      const float s = (r >> 3) == 2 ? 2.f * L2E : L2E;
#pragma unroll
      for (int j = 0; j < 4; ++j) {
        float2 v = ((const float2*)(Whh1 + r * 8))[j];
        whh2[r * 4 + j] = packf16(v.x * s, v.y * s);
      }
    }
    int wxb[32];
#pragma unroll
    for (int r = 0; r < 32; ++r) {
      const float s = (r >> 3) == 2 ? 2.f * L2E : L2E;
      wxb[r] = packf16(Wih1[r] * s, (bih1[r] + bhh1[r]) * s);
    }
#pragma unroll
    for (int i = 0; i < 128; i += 8)
      asm volatile("" : "+v"(whh2[i]), "+v"(whh2[i + 1]), "+v"(whh2[i + 2]),
                        "+v"(whh2[i + 3]), "+v"(whh2[i + 4]), "+v"(whh2[i + 5]),
                        "+v"(whh2[i + 6]), "+v"(whh2[i + 7]));

#pragma unroll 1
    for (int ch = 0; ch < 4; ++ch) {
      const int c = ch * 512 + t;  // chain index within this block's 2 seqs
      const float* __restrict__ xp = x + ((size_t)b * 2048 + c) * 16;
      float cc[8];
      int h2[4];
#pragma unroll
      for (int k = 0; k < 8; ++k) cc[k] = 0.f;
#pragma unroll
      for (int j = 0; j < 4; ++j) h2[j] = 0;

      float xv = xp[0];
#pragma unroll 1
      for (int u = 0; u < 16; ++u) {
        float xnl = xp[(u + 1) & 15];  // 1-ahead prefetch (same line, L1 hit)
        const int xt1 = packf16(xv, 1.f);
        float hn[8];
#pragma unroll
        for (int k = 0; k < 8; ++k) {
          float acc[4];
#pragma unroll
          for (int gi = 0; gi < 4; ++gi) {
            const int r = gi * 8 + k;
            float a = dot2(wxb[r], xt1, 0.f);
            a = dot2(whh2[r * 4 + 0], h2[0], a);
            a = dot2(whh2[r * 4 + 1], h2[1], a);
            a = dot2(whh2[r * 4 + 2], h2[2], a);
            a = dot2(whh2[r * 4 + 3], h2[3], a);
            acc[gi] = a;
          }
          float iv = sig2(acc[0]), fv = sig2(acc[1]);
          float gv = fmaf(2.f, sig2(acc[2]), -1.f), ov = sig2(acc[3]);
          cc[k] = fmaf(fv, cc[k], iv * gv);
          hn[k] = ov * tanhc(cc[k]);
        }
#pragma unroll
        for (int j = 0; j < 4; ++j) h2[j] = packf16(hn[2 * j], hn[2 * j + 1]);
        xv = xnl;
      }
      int4 o;
      o.x = h2[0]; o.y = h2[1]; o.z = h2[2]; o.w = h2[3];
      sX2[c >> 10][c & 1023] = o;  // coalesced ds_write_b128
    }
  }

  // ======================== Phase 2: lstm2 x2 ========================
  const int sq = t >> 8;    // which sequence this thread-half runs
  const int tl = t & 255;   // thread index within the sequence group
  const int m = tl >> 1;    // hidden index (0..127)
  const int q = tl & 1;     // K-half and DPP pair lane (== lane&1)
  const bool isq1 = (q == 1);

  // K-half q of all four gate rows of index m, log2e-folded per gate.
  int w[128];
#pragma unroll
  for (int g = 0; g < 4; ++g) {
    const float s = (g == 2) ? 2.f * L2E : L2E;
    const float2* p = (const float2*)(Whh2 + (size_t)(g * 128 + m) * 128 + q * 64);
#pragma unroll
    for (int j = 0; j < 32; ++j) {
      float2 v = p[j];
      w[g * 32 + j] = packf16(v.x * s, v.y * s);
    }
  }
#pragma unroll
  for (int i = 0; i < 128; i += 8)
    asm volatile("" : "+v"(w[i]), "+v"(w[i + 1]), "+v"(w[i + 2]),
                      "+v"(w[i + 3]), "+v"(w[i + 4]), "+v"(w[i + 5]),
                      "+v"(w[i + 6]), "+v"(w[i + 7]));

  // x rows + biases for the two gates this thread finalizes:
  // gate A = 2q (i or g), gate B = 2q+1 (f or o).
  int wigA[4], wigB[4];
  float biasA, biasB;
  {
    const int gA = 2 * q, gB = 2 * q + 1;
    const float sa = (gA == 2) ? 2.f * L2E : L2E;
    const float sb = L2E;  // gates 1 and 3 are sigmoids
    const int rowA = gA * 128 + m;
    const int rowB = gB * 128 + m;
    const float2* pa = (const float2*)(Wih2 + (size_t)rowA * 8);
    const float2* pb = (const float2*)(Wih2 + (size_t)rowB * 8);
#pragma unroll
    for (int j = 0; j < 4; ++j) {
      float2 va = pa[j], vb = pb[j];
      wigA[j] = packf16(va.x * sa, va.y * sa);
      wigB[j] = packf16(vb.x * sb, vb.y * sb);
    }
    biasA = (bih2[rowA] + bhh2[rowA]) * sa;
    biasB = (bih2[rowB] + bhh2[rowB]) * sb;
  }

  int hq[32];  // this thread's h-half (64 f16)
#pragma unroll
  for (int i = 0; i < 32; ++i) hq[i] = 0;
  float c = 0.f;

  const int4* __restrict__ sXs = sX2[sq];
  _Float16 (* __restrict__ sHs)[128] = sH2[sq];

  __syncthreads();   // sX2 fully written
  int4 xc = sXs[0];

#define LSTM2_STEP(BUF, NEXT_IDX)                                          \
  {                                                                        \
    float bxA = biasA, bxB = biasB;                                        \
    bxA = dot2(wigA[0], xc.x, bxA);                                        \
    bxA = dot2(wigA[1], xc.y, bxA);                                        \
    bxA = dot2(wigA[2], xc.z, bxA);                                        \
    bxA = dot2(wigA[3], xc.w, bxA);                                        \
    bxB = dot2(wigB[0], xc.x, bxB);                                        \
    bxB = dot2(wigB[1], xc.y, bxB);                                        \
    bxB = dot2(wigB[2], xc.z, bxB);                                        \
    bxB = dot2(wigB[3], xc.w, bxB);                                        \
    float R0a = 0.f, R1a = 0.f, R2a = 0.f, R3a = 0.f;                      \
    float R0b = 0.f, R1b = 0.f, R2b = 0.f, R3b = 0.f;                      \
    _Pragma("unroll")                                                      \
    for (int j = 0; j < 16; ++j) {                                         \
      R0a = dot2(w[j], hq[j], R0a);                                        \
      R1a = dot2(w[32 + j], hq[j], R1a);                                   \
      R2a = dot2(w[64 + j], hq[j], R2a);                                   \
      R3a = dot2(w[96 + j], hq[j], R3a);                                   \
    }                                                                      \
    _Pragma("unroll")                                                      \
    for (int j = 16; j < 32; ++j) {                                        \
      R0b = dot2(w[j], hq[j], R0b);                                        \
      R1b = dot2(w[32 + j], hq[j], R1b);                                   \
      R2b = dot2(w[64 + j], hq[j], R2b);                                   \
      R3b = dot2(w[96 + j], hq[j], R3b);                                   \
    }                                                                      \
    float R0 = R0a + R0b, R1 = R1a + R1b;                                  \
    float R2 = R2a + R2b, R3 = R3a + R3b;                                  \
    float vA = isq1 ? R0 : R2;                                             \
    float Sa = (isq1 ? R2 : R0) + qp<QP_X1>(vA) + bxA;                     \
    float vB = isq1 ? R1 : R3;                                             \
    float Sb = (isq1 ? R3 : R1) + qp<QP_X1>(vB) + bxB;                     \
    float sga = sig2(Sa);                                                  \
    float actA = isq1 ? fmaf(2.f, sga, -1.f) : sga;                        \
    float actB = sig2(Sb);                                                 \
    float ga = qp<QP_X1>(actA);                                            \
    float gb = qp<QP_X1>(actB);                                            \
    float iv = isq1 ? ga : actA;                                           \
    float gv = isq1 ? actA : ga;                                           \
    float fv = isq1 ? gb : actB;                                           \
    float ov = isq1 ? actB : gb;                                           \
    c = fmaf(fv, c, iv * gv);                                              \
    float hx = ov * tanhc(c);                                              \
    if (!isq1) sHs[BUF][m] = (_Float16)hx;                                 \
    __syncthreads();                                                       \
    const int4* src = (const int4*)(&sHs[BUF][q * 64]);                    \
    int4 A = src[0], Bv = src[1], C = src[2], D = src[3];                  \
    int4 E = src[4], F = src[5], G2 = src[6], H = src[7];                  \
    hq[0] = A.x;   hq[1] = A.y;   hq[2] = A.z;   hq[3] = A.w;              \
    hq[4] = Bv.x;  hq[5] = Bv.y;  hq[6] = Bv.z;  hq[7] = Bv.w;             \
    hq[8] = C.x;   hq[9] = C.y;   hq[10] = C.z;  hq[11] = C.w;             \
    hq[12] = D.x;  hq[13] = D.y;  hq[14] = D.z;  hq[15] = D.w;             \
    hq[16] = E.x;  hq[17] = E.y;  hq[18] = E.z;  hq[19] = E.w;             \
    hq[20] = F.x;  hq[21] = F.y;  hq[22] = F.z;  hq[23] = F.w;             \
    hq[24] = G2.x; hq[25] = G2.y; hq[26] = G2.z; hq[27] = G2.w;            \
    hq[28] = H.x;  hq[29] = H.y;  hq[30] = H.z;  hq[31] = H.w;             \
    xc = sXs[NEXT_IDX];                                                    \
  }

#pragma unroll 1
  for (int ts2 = 0; ts2 < 512; ++ts2) {
    LSTM2_STEP(0, 2 * ts2 + 1)
    LSTM2_STEP(1, 2 * ts2 + 2)
  }
#undef LSTM2_STEP

  // Epilogue: out[2b+sq] = (h @ Wd1.T + bd1) @ Wd2.T + bd2; h_T in sHs[1].
  // tl<64 selects wave 0 (seq 0) and wave 4 (seq 1) -> full-wave reductions.
  if (tl < 64) {
    float a = bd1[tl];
#pragma unroll
    for (int k = 0; k < 128; ++k)
      a = fmaf(Wd1[tl * 128 + k], (float)sHs[1][k], a);
    float v = a * Wd2[tl];
#pragma unroll
    for (int off = 32; off > 0; off >>= 1) v += __shfl_down(v, off);
    if (tl == 0) out[2 * b + sq] = v + bd2[0];
  }
}

extern "C" void kernel_launch(void* const* d_in, const int* in_sizes, int n_in,
                              void* d_out, int out_size, void* d_ws, size_t ws_size,
                              hipStream_t stream) {
  const float* x    = (const float*)d_in[0];
  // d_in[1] is the unused python scalar `data`
  const float* Wih1 = (const float*)d_in[2];
  const float* Whh1 = (const float*)d_in[3];
  const float* bih1 = (const float*)d_in[4];
  const float* bhh1 = (const float*)d_in[5];
  const float* Wih2 = (const float*)d_in[6];
  const float* Whh2 = (const float*)d_in[7];
  const float* bih2 = (const float*)d_in[8];
  const float* bhh2 = (const float*)d_in[9];
  const float* W1   = (const float*)d_in[10];
  const float* b1   = (const float*)d_in[11];
  const float* W2   = (const float*)d_in[12];
  const float* b2   = (const float*)d_in[13];
  float* out = (float*)d_out;

  fused_kernel<<<128, 512, 0, stream>>>(x, Wih1, Whh1, bih1, bhh1,
                                        Wih2, Whh2, bih2, bhh2,
                                        W1, b1, W2, b2, out);
}

// Round 6
// 1042.273 us; speedup vs baseline: 1.0371x; 1.0371x over previous
//
#include <hip/hip_runtime.h>
#include <cstdint>

typedef _Float16 f16x2 __attribute__((ext_vector_type(2)));

#define L2E 1.44269504f

// Activations with log2(e) pre-folded into weights/biases:
// sig2(y) = 1/(1+2^-y)  (y = x*log2e already)
__device__ __forceinline__ float sig2(float y) {
  return __builtin_amdgcn_rcpf(1.f + exp2f(-y));
}
// tanh for runtime (unscaled) cell state c
__device__ __forceinline__ float tanhc(float c) {
  return fmaf(2.f, __builtin_amdgcn_rcpf(1.f + exp2f(c * (-2.f * L2E))), -1.f);
}
__device__ __forceinline__ int packf16(float a, float b) {
  f16x2 p; p.x = (_Float16)a; p.y = (_Float16)b;
  return __builtin_bit_cast(int, p);
}

// ---------------------------------------------------------------------------
// R6 core change: v_dot2_f32_f16 (fdot2) is ~quarter-rate on gfx950 (the
// only model fitting R1/R4/R5 intervals AND VALUBusy once R5's idle-CU
// normalization is applied). v_fma_mix_f32 is a full-rate VOP3P op with f16
// sources (op_sel) and f32 accumulate -> 2 MACs in ~4 cyc instead of ~7.3,
// with IDENTICAL numerics (exact f16->f32 convert + f32 fma).
// ---------------------------------------------------------------------------
__device__ __forceinline__ float mixlo(int w, int h, float acc) {
  asm("v_fma_mix_f32 %0, %1, %2, %0 op_sel_hi:[1,1,0]"
      : "+v"(acc) : "v"(w), "v"(h));
  return acc;
}
__device__ __forceinline__ float mixhi(int w, int h, float acc) {
  asm("v_fma_mix_f32 %0, %1, %2, %0 op_sel:[1,1,0] op_sel_hi:[1,1,0]"
      : "+v"(acc) : "v"(w), "v"(h));
  return acc;
}
__device__ __forceinline__ float dot2m(int w, int h, float acc) {
  return mixhi(w, h, mixlo(w, h, acc));
}

// Pair-lane permute via DPP quad_perm (lane ^ 1): ~4 cyc VALU.
template <int CTRL>
__device__ __forceinline__ float qp(float v) {
  return __int_as_float(__builtin_amdgcn_update_dpp(
      0, __float_as_int(v), CTRL, 0xF, 0xF, true));
}
#define QP_X1 0xB1  // quad_perm [1,0,3,2]  (lane ^ 1)

// ---------------------------------------------------------------------------
// FUSED kernel (R4 structure byte-identical except dot2 -> fma_mix pairs):
// 256 blocks x 256 threads, phase 1 = lstm1 into sX LDS, phase 2 = lstm2
// half-K split with DPP pair reduce, one barrier per step.
// ---------------------------------------------------------------------------
__global__ __launch_bounds__(256, 1) void fused_kernel(
    const float* __restrict__ x, const float* __restrict__ Wih1,
    const float* __restrict__ Whh1, const float* __restrict__ bih1,
    const float* __restrict__ bhh1, const float* __restrict__ Wih2,
    const float* __restrict__ Whh2, const float* __restrict__ bih2,
    const float* __restrict__ bhh2, const float* __restrict__ Wd1,
    const float* __restrict__ bd1, const float* __restrict__ Wd2,
    const float* __restrict__ bd2, float* __restrict__ out) {
  __shared__ __align__(16) int4 sX[1026];        // h1 sequence (16 KB) + pad
  __shared__ __align__(16) _Float16 sH[2][128];  // double-buffered h

  const int b = blockIdx.x;
  const int t = threadIdx.x;

  // ======================== Phase 1: lstm1 ========================
  {
    // Block-uniform weights, log2e-folded (gate order i,f,g,o; g rows x2).
    int whh2[128];
#pragma unroll
    for (int r = 0; r < 32; ++r) {
      const float s = (r >> 3) == 2 ? 2.f * L2E : L2E;
#pragma unroll
      for (int j = 0; j < 4; ++j) {
        float2 v = ((const float2*)(Whh1 + r * 8))[j];
        whh2[r * 4 + j] = packf16(v.x * s, v.y * s);
      }
    }
    int wxb[32];
#pragma unroll
    for (int r = 0; r < 32; ++r) {
      const float s = (r >> 3) == 2 ? 2.f * L2E : L2E;
      wxb[r] = packf16(Wih1[r] * s, (bih1[r] + bhh1[r]) * s);
    }
#pragma unroll
    for (int i = 0; i < 128; i += 8)
      asm volatile("" : "+v"(whh2[i]), "+v"(whh2[i + 1]), "+v"(whh2[i + 2]),
                        "+v"(whh2[i + 3]), "+v"(whh2[i + 4]), "+v"(whh2[i + 5]),
                        "+v"(whh2[i + 6]), "+v"(whh2[i + 7]));

#pragma unroll 1
    for (int ch = 0; ch < 4; ++ch) {
      const int c = ch * 256 + t;  // chain index within this batch row
      const float* __restrict__ xp = x + ((size_t)b * 1024 + c) * 16;
      float cc[8];
      int h2[4];
#pragma unroll
      for (int k = 0; k < 8; ++k) cc[k] = 0.f;
#pragma unroll
      for (int j = 0; j < 4; ++j) h2[j] = 0;

      float xv = xp[0];
#pragma unroll 1
      for (int u = 0; u < 16; ++u) {
        float xnl = xp[(u + 1) & 15];  // 1-ahead prefetch (same line, L1 hit)
        const int xt1 = packf16(xv, 1.f);
        float hn[8];
#pragma unroll
        for (int k = 0; k < 8; ++k) {
          float acc[4];
#pragma unroll
          for (int gi = 0; gi < 4; ++gi) {
            const int r = gi * 8 + k;
            float a = dot2m(wxb[r], xt1, 0.f);
            a = dot2m(whh2[r * 4 + 0], h2[0], a);
            a = dot2m(whh2[r * 4 + 1], h2[1], a);
            a = dot2m(whh2[r * 4 + 2], h2[2], a);
            a = dot2m(whh2[r * 4 + 3], h2[3], a);
            acc[gi] = a;
          }
          float iv = sig2(acc[0]), fv = sig2(acc[1]);
          float gv = fmaf(2.f, sig2(acc[2]), -1.f), ov = sig2(acc[3]);
          cc[k] = fmaf(fv, cc[k], iv * gv);
          hn[k] = ov * tanhc(cc[k]);
        }
#pragma unroll
        for (int j = 0; j < 4; ++j) h2[j] = packf16(hn[2 * j], hn[2 * j + 1]);
        xv = xnl;
      }
      int4 o;
      o.x = h2[0]; o.y = h2[1]; o.z = h2[2]; o.w = h2[3];
      sX[c] = o;  // coalesced ds_write_b128, lanes contiguous
    }
  }

  // ======================== Phase 2: lstm2 ========================
  const int m = t >> 1;  // hidden index (0..127)
  const int q = t & 1;   // K-half and DPP pair lane
  const bool isq1 = (q == 1);

  // K-half q of all four gate rows of index m, log2e-folded per gate.
  int w[128];
#pragma unroll
  for (int g = 0; g < 4; ++g) {
    const float s = (g == 2) ? 2.f * L2E : L2E;
    const float2* p = (const float2*)(Whh2 + (size_t)(g * 128 + m) * 128 + q * 64);
#pragma unroll
    for (int j = 0; j < 32; ++j) {
      float2 v = p[j];
      w[g * 32 + j] = packf16(v.x * s, v.y * s);
    }
  }
#pragma unroll
  for (int i = 0; i < 128; i += 8)
    asm volatile("" : "+v"(w[i]), "+v"(w[i + 1]), "+v"(w[i + 2]),
                      "+v"(w[i + 3]), "+v"(w[i + 4]), "+v"(w[i + 5]),
                      "+v"(w[i + 6]), "+v"(w[i + 7]));

  // x rows + biases for the two gates this thread finalizes:
  // gate A = 2q (i or g), gate B = 2q+1 (f or o).
  int wigA[4], wigB[4];
  float biasA, biasB;
  {
    const int gA = 2 * q, gB = 2 * q + 1;
    const float sa = (gA == 2) ? 2.f * L2E : L2E;
    const float sb = L2E;  // gates 1 and 3 are sigmoids
    const int rowA = gA * 128 + m;
    const int rowB = gB * 128 + m;
    const float2* pa = (const float2*)(Wih2 + (size_t)rowA * 8);
    const float2* pb = (const float2*)(Wih2 + (size_t)rowB * 8);
#pragma unroll
    for (int j = 0; j < 4; ++j) {
      float2 va = pa[j], vb = pb[j];
      wigA[j] = packf16(va.x * sa, va.y * sa);
      wigB[j] = packf16(vb.x * sb, vb.y * sb);
    }
    biasA = (bih2[rowA] + bhh2[rowA]) * sa;
    biasB = (bih2[rowB] + bhh2[rowB]) * sb;
  }

  int hq[32];  // this thread's h-half (64 f16)
#pragma unroll
  for (int i = 0; i < 32; ++i) hq[i] = 0;
  float c = 0.f;

  __syncthreads();   // sX fully written
  int4 xc = sX[0];

#define LSTM2_STEP(BUF, NEXT_IDX)                                          \
  {                                                                        \
    float bxA = biasA, bxB = biasB;                                        \
    bxA = dot2m(wigA[0], xc.x, bxA);                                       \
    bxA = dot2m(wigA[1], xc.y, bxA);                                       \
    bxA = dot2m(wigA[2], xc.z, bxA);                                       \
    bxA = dot2m(wigA[3], xc.w, bxA);                                       \
    bxB = dot2m(wigB[0], xc.x, bxB);                                       \
    bxB = dot2m(wigB[1], xc.y, bxB);                                       \
    bxB = dot2m(wigB[2], xc.z, bxB);                                       \
    bxB = dot2m(wigB[3], xc.w, bxB);                                       \
    float R0a = 0.f, R1a = 0.f, R2a = 0.f, R3a = 0.f;                      \
    float R0b = 0.f, R1b = 0.f, R2b = 0.f, R3b = 0.f;                      \
    _Pragma("unroll")                                                      \
    for (int j = 0; j < 16; ++j) {                                         \
      R0a = dot2m(w[j], hq[j], R0a);                                       \
      R1a = dot2m(w[32 + j], hq[j], R1a);                                  \
      R2a = dot2m(w[64 + j], hq[j], R2a);                                  \
      R3a = dot2m(w[96 + j], hq[j], R3a);                                  \
    }                                                                      \
    _Pragma("unroll")                                                      \
    for (int j = 16; j < 32; ++j) {                                        \
      R0b = dot2m(w[j], hq[j], R0b);                                       \
      R1b = dot2m(w[32 + j], hq[j], R1b);                                  \
      R2b = dot2m(w[64 + j], hq[j], R2b);                                  \
      R3b = dot2m(w[96 + j], hq[j], R3b);                                  \
    }                                                                      \
    float R0 = R0a + R0b, R1 = R1a + R1b;                                  \
    float R2 = R2a + R2b, R3 = R3a + R3b;                                  \
    float vA = isq1 ? R0 : R2;                                             \
    float Sa = (isq1 ? R2 : R0) + qp<QP_X1>(vA) + bxA;                     \
    float vB = isq1 ? R1 : R3;                                             \
    float Sb = (isq1 ? R3 : R1) + qp<QP_X1>(vB) + bxB;                     \
    float sga = sig2(Sa);                                                  \
    float actA = isq1 ? fmaf(2.f, sga, -1.f) : sga;                        \
    float actB = sig2(Sb);                                                 \
    float ga = qp<QP_X1>(actA);                                            \
    float gb = qp<QP_X1>(actB);                                            \
    float iv = isq1 ? ga : actA;                                           \
    float gv = isq1 ? actA : ga;                                           \
    float fv = isq1 ? gb : actB;                                           \
    float ov = isq1 ? actB : gb;                                           \
    c = fmaf(fv, c, iv * gv);                                              \
    float hx = ov * tanhc(c);                                              \
    if (!isq1) sH[BUF][m] = (_Float16)hx;                                  \
    __syncthreads();                                                       \
    const int4* src = (const int4*)(&sH[BUF][q * 64]);                     \
    int4 A = src[0], Bv = src[1], C = src[2], D = src[3];                  \
    int4 E = src[4], F = src[5], G2 = src[6], H = src[7];                  \
    hq[0] = A.x;   hq[1] = A.y;   hq[2] = A.z;   hq[3] = A.w;              \
    hq[4] = Bv.x;  hq[5] = Bv.y;  hq[6] = Bv.z;  hq[7] = Bv.w;             \
    hq[8] = C.x;   hq[9] = C.y;   hq[10] = C.z;  hq[11] = C.w;             \
    hq[12] = D.x;  hq[13] = D.y;  hq[14] = D.z;  hq[15] = D.w;             \
    hq[16] = E.x;  hq[17] = E.y;  hq[18] = E.z;  hq[19] = E.w;             \
    hq[20] = F.x;  hq[21] = F.y;  hq[22] = F.z;  hq[23] = F.w;             \
    hq[24] = G2.x; hq[25] = G2.y; hq[26] = G2.z; hq[27] = G2.w;            \
    hq[28] = H.x;  hq[29] = H.y;  hq[30] = H.z;  hq[31] = H.w;             \
    xc = sX[NEXT_IDX];                                                     \
  }

#pragma unroll 1
  for (int ts2 = 0; ts2 < 512; ++ts2) {
    LSTM2_STEP(0, 2 * ts2 + 1)
    LSTM2_STEP(1, 2 * ts2 + 2)
  }
#undef LSTM2_STEP

  // Epilogue: out[b] = (h @ Wd1.T + bd1) @ Wd2.T + bd2; h_T is in sH[1].
  if (t < 64) {
    float a = bd1[t];
#pragma unroll
    for (int k = 0; k < 128; ++k)
      a = fmaf(Wd1[t * 128 + k], (float)sH[1][k], a);
    float v = a * Wd2[t];
#pragma unroll
    for (int off = 32; off > 0; off >>= 1) v += __shfl_down(v, off);
    if (t == 0) out[b] = v + bd2[0];
  }
}

extern "C" void kernel_launch(void* const* d_in, const int* in_sizes, int n_in,
                              void* d_out, int out_size, void* d_ws, size_t ws_size,
                              hipStream_t stream) {
  const float* x    = (const float*)d_in[0];
  // d_in[1] is the unused python scalar `data`
  const float* Wih1 = (const float*)d_in[2];
  const float* Whh1 = (const float*)d_in[3];
  const float* bih1 = (const float*)d_in[4];
  const float* bhh1 = (const float*)d_in[5];
  const float* Wih2 = (const float*)d_in[6];
  const float* Whh2 = (const float*)d_in[7];
  const float* bih2 = (const float*)d_in[8];
  const float* bhh2 = (const float*)d_in[9];
  const float* W1   = (const float*)d_in[10];
  const float* b1   = (const float*)d_in[11];
  const float* W2   = (const float*)d_in[12];
  const float* b2   = (const float*)d_in[13];
  float* out = (float*)d_out;

  fused_kernel<<<256, 256, 0, stream>>>(x, Wih1, Whh1, bih1, bhh1,
                                        Wih2, Whh2, bih2, bhh2,
                                        W1, b1, W2, b2, out);
}

// Round 7
// 832.035 us; speedup vs baseline: 1.2992x; 1.2527x over previous
//
#include <hip/hip_runtime.h>
#include <cstdint>

typedef _Float16 f16x2 __attribute__((ext_vector_type(2)));

#define L2E 1.44269504f

// sig2(y) = 1/(1+2^-y)  (y pre-scaled by log2e via weights)
__device__ __forceinline__ float sig2(float y) {
  return __builtin_amdgcn_rcpf(1.f + exp2f(-y));
}
// tanh for runtime (unscaled) cell state c
__device__ __forceinline__ float tanhc(float c) {
  return fmaf(2.f, __builtin_amdgcn_rcpf(1.f + exp2f(c * (-2.f * L2E))), -1.f);
}
__device__ __forceinline__ int packf16(float a, float b) {
  f16x2 p; p.x = (_Float16)a; p.y = (_Float16)b;
  return __builtin_bit_cast(int, p);
}
__device__ __forceinline__ float dot2(int w, int h, float acc) {
  return __builtin_amdgcn_fdot2(__builtin_bit_cast(f16x2, w),
                                __builtin_bit_cast(f16x2, h), acc, false);
}
// Quad-lane permute via DPP (VALU ~4 cyc).
template <int CTRL>
__device__ __forceinline__ float qp(float v) {
  return __int_as_float(__builtin_amdgcn_update_dpp(
      0, __float_as_int(v), CTRL, 0xF, 0xF, true));
}
#define QP_X1 0xB1  // quad_perm [1,0,3,2]  (lane ^ 1)
#define QP_X2 0x4E  // quad_perm [2,3,0,1]  (lane ^ 2)

// ---------------------------------------------------------------------------
// R7: PHASE 2 IN FULL-RATE f32 FMA. Measured instruction rates on gfx950
// (fits R1/R4/R5/R6 within 3%): v_dot2_f32_f16 ~7.3 cyc, v_fma_mix_f32
// ~7.2 cyc (R6: +136 insts -> +980 cyc/step), v_fma_f32 = 2 cyc (verified
// full-rate). So phase 2 switches to f32 weights/h and plain fma:
//   - 512 threads/block (256 blocks = 1/CU), K-QUARTER per thread, R0-style
//     quad DPP transpose-reduce. 2 waves/SIMD for latency hiding WITHOUT
//     halving the grid (R5's error).
//   - w = 4 gates x 32 f32 = 128 VGPR/thread; ~205 live regs < 256 cap.
//   - h, x staged in LDS as f32 (no pack/unpack; better numerics).
// Phase 1 stays packed-f16 dot2 (register-bound; ~31 us at 2 chains/thread).
// ---------------------------------------------------------------------------
__global__ __launch_bounds__(512, 2) void fused_kernel(
    const float* __restrict__ x, const float* __restrict__ Wih1,
    const float* __restrict__ Whh1, const float* __restrict__ bih1,
    const float* __restrict__ bhh1, const float* __restrict__ Wih2,
    const float* __restrict__ Whh2, const float* __restrict__ bih2,
    const float* __restrict__ bhh2, const float* __restrict__ Wd1,
    const float* __restrict__ bd1, const float* __restrict__ Wd2,
    const float* __restrict__ bd2, float* __restrict__ out) {
  __shared__ __align__(16) float sXf[1026][8];   // h1 sequence, f32 (32.8 KB)
  __shared__ __align__(16) float sHf[2][128];    // double-buffered h, f32

  const int b = blockIdx.x;
  const int t = threadIdx.x;

  // ======================== Phase 1: lstm1 (dot2) ========================
  {
    int whh2[128];
#pragma unroll
    for (int r = 0; r < 32; ++r) {
      const float s = (r >> 3) == 2 ? 2.f * L2E : L2E;
#pragma unroll
      for (int j = 0; j < 4; ++j) {
        float2 v = ((const float2*)(Whh1 + r * 8))[j];
        whh2[r * 4 + j] = packf16(v.x * s, v.y * s);
      }
    }
    int wxb[32];
#pragma unroll
    for (int r = 0; r < 32; ++r) {
      const float s = (r >> 3) == 2 ? 2.f * L2E : L2E;
      wxb[r] = packf16(Wih1[r] * s, (bih1[r] + bhh1[r]) * s);
    }
#pragma unroll
    for (int i = 0; i < 128; i += 8)
      asm volatile("" : "+v"(whh2[i]), "+v"(whh2[i + 1]), "+v"(whh2[i + 2]),
                        "+v"(whh2[i + 3]), "+v"(whh2[i + 4]), "+v"(whh2[i + 5]),
                        "+v"(whh2[i + 6]), "+v"(whh2[i + 7]));

#pragma unroll 1
    for (int ch = 0; ch < 2; ++ch) {
      const int c = ch * 512 + t;  // chain index within this batch row
      const float* __restrict__ xp = x + ((size_t)b * 1024 + c) * 16;
      float cc[8];
      int h2[4];
#pragma unroll
      for (int k = 0; k < 8; ++k) cc[k] = 0.f;
#pragma unroll
      for (int j = 0; j < 4; ++j) h2[j] = 0;

      float hn[8];
      float xv = xp[0];
#pragma unroll 1
      for (int u = 0; u < 16; ++u) {
        float xnl = xp[(u + 1) & 15];  // 1-ahead prefetch (same line)
        const int xt1 = packf16(xv, 1.f);
#pragma unroll
        for (int k = 0; k < 8; ++k) {
          float acc[4];
#pragma unroll
          for (int gi = 0; gi < 4; ++gi) {
            const int r = gi * 8 + k;
            float a = dot2(wxb[r], xt1, 0.f);
            a = dot2(whh2[r * 4 + 0], h2[0], a);
            a = dot2(whh2[r * 4 + 1], h2[1], a);
            a = dot2(whh2[r * 4 + 2], h2[2], a);
            a = dot2(whh2[r * 4 + 3], h2[3], a);
            acc[gi] = a;
          }
          float iv = sig2(acc[0]), fv = sig2(acc[1]);
          float gv = fmaf(2.f, sig2(acc[2]), -1.f), ov = sig2(acc[3]);
          cc[k] = fmaf(fv, cc[k], iv * gv);
          hn[k] = ov * tanhc(cc[k]);
        }
#pragma unroll
        for (int j = 0; j < 4; ++j) h2[j] = packf16(hn[2 * j], hn[2 * j + 1]);
        xv = xnl;
      }
      // store final h as f32 directly (2 x ds_write_b128)
      float4* dst = (float4*)sXf[c];
      float4 o0, o1;
      o0.x = hn[0]; o0.y = hn[1]; o0.z = hn[2]; o0.w = hn[3];
      o1.x = hn[4]; o1.y = hn[5]; o1.z = hn[6]; o1.w = hn[7];
      dst[0] = o0; dst[1] = o1;
    }
  }

  // ======================== Phase 2: lstm2 (f32 fma) ========================
  const int m = t >> 2;  // hidden index (0..127)
  const int q = t & 3;   // K-quarter = DPP quad lane
  const int G = ((q & 1) << 1) | (q >> 1);  // gate this thread finalizes
  const bool sel0 = (q & 1) != 0;
  const bool sel1 = (q & 2) != 0;
  const bool isq0 = (q == 0);
  const bool isq1 = (q == 1);  // G==2 (tanh gate)

  // K-quarter q of all four gate rows of index m, f32, log2e-folded per gate.
  float w[128];
#pragma unroll
  for (int g = 0; g < 4; ++g) {
    const float s = (g == 2) ? 2.f * L2E : L2E;
    const float4* p = (const float4*)(Whh2 + (size_t)(g * 128 + m) * 128 + q * 32);
#pragma unroll
    for (int j = 0; j < 8; ++j) {
      float4 v = p[j];
      w[g * 32 + 4 * j + 0] = v.x * s;
      w[g * 32 + 4 * j + 1] = v.y * s;
      w[g * 32 + 4 * j + 2] = v.z * s;
      w[g * 32 + 4 * j + 3] = v.w * s;
    }
  }
#pragma unroll
  for (int i = 0; i < 128; i += 8)
    asm volatile("" : "+v"(w[i]), "+v"(w[i + 1]), "+v"(w[i + 2]),
                      "+v"(w[i + 3]), "+v"(w[i + 4]), "+v"(w[i + 5]),
                      "+v"(w[i + 6]), "+v"(w[i + 7]));

  // x row + bias for the gate this thread finalizes (row G*128+m), f32.
  float wig[8];
  float bias;
  {
    const float s = (G == 2) ? 2.f * L2E : L2E;
    const float4* pi = (const float4*)(Wih2 + (size_t)(G * 128 + m) * 8);
    float4 a = pi[0], bv = pi[1];
    wig[0] = a.x * s;  wig[1] = a.y * s;  wig[2] = a.z * s;  wig[3] = a.w * s;
    wig[4] = bv.x * s; wig[5] = bv.y * s; wig[6] = bv.z * s; wig[7] = bv.w * s;
    bias = (bih2[G * 128 + m] + bhh2[G * 128 + m]) * s;
  }

  float hq[32];  // this thread's h-quarter (32 f32)
#pragma unroll
  for (int i = 0; i < 32; ++i) hq[i] = 0.f;
  float c = 0.f;

  __syncthreads();  // sXf fully written
  float4 xc0 = ((const float4*)sXf[0])[0];
  float4 xc1 = ((const float4*)sXf[0])[1];

#define LSTM2_STEP(BUF, NEXT_IDX)                                          \
  {                                                                        \
    float bx = bias;                                                       \
    bx = fmaf(wig[0], xc0.x, bx);                                          \
    bx = fmaf(wig[1], xc0.y, bx);                                          \
    bx = fmaf(wig[2], xc0.z, bx);                                          \
    bx = fmaf(wig[3], xc0.w, bx);                                          \
    bx = fmaf(wig[4], xc1.x, bx);                                          \
    bx = fmaf(wig[5], xc1.y, bx);                                          \
    bx = fmaf(wig[6], xc1.z, bx);                                          \
    bx = fmaf(wig[7], xc1.w, bx);                                          \
    float R0a = 0.f, R1a = 0.f, R2a = 0.f, R3a = 0.f;                      \
    float R0b = 0.f, R1b = 0.f, R2b = 0.f, R3b = 0.f;                      \
    _Pragma("unroll")                                                      \
    for (int j = 0; j < 16; ++j) {                                         \
      R0a = fmaf(w[j], hq[j], R0a);                                        \
      R1a = fmaf(w[32 + j], hq[j], R1a);                                   \
      R2a = fmaf(w[64 + j], hq[j], R2a);                                   \
      R3a = fmaf(w[96 + j], hq[j], R3a);                                   \
    }                                                                      \
    _Pragma("unroll")                                                      \
    for (int j = 16; j < 32; ++j) {                                        \
      R0b = fmaf(w[j], hq[j], R0b);                                        \
      R1b = fmaf(w[32 + j], hq[j], R1b);                                   \
      R2b = fmaf(w[64 + j], hq[j], R2b);                                   \
      R3b = fmaf(w[96 + j], hq[j], R3b);                                   \
    }                                                                      \
    float R0 = R0a + R0b, R1 = R1a + R1b;                                  \
    float R2 = R2a + R2b, R3 = R3a + R3b;                                  \
    float s0 = sel0 ? R0 : R2, s1 = sel0 ? R1 : R3;                        \
    float k0 = sel0 ? R2 : R0, k1 = sel0 ? R3 : R1;                        \
    float S0 = k0 + qp<QP_X1>(s0);                                         \
    float S1 = k1 + qp<QP_X1>(s1);                                         \
    float s2 = sel1 ? S0 : S1;                                             \
    float k2 = sel1 ? S1 : S0;                                             \
    float S = k2 + qp<QP_X2>(s2) + bx;                                     \
    float sg = sig2(S);                                                    \
    float act = isq1 ? fmaf(2.f, sg, -1.f) : sg;                           \
    float v0 = act;                                                        \
    float v1 = qp<QP_X1>(v0);                                              \
    float v2 = qp<QP_X2>(v0);                                              \
    float v3 = qp<QP_X2>(v1);                                              \
    float p01 = sel0 ? v1 : v0, p23 = sel0 ? v3 : v2;                      \
    float q01 = sel0 ? v0 : v1, q23 = sel0 ? v2 : v3;                      \
    float iv = sel1 ? p23 : p01;                                           \
    float fv = sel1 ? p01 : p23;                                           \
    float gv = sel1 ? q23 : q01;                                           \
    float ov = sel1 ? q01 : q23;                                           \
    c = fmaf(fv, c, iv * gv);                                              \
    float hx = ov * tanhc(c);                                              \
    if (isq0) sHf[BUF][m] = hx;                                            \
    __syncthreads();                                                       \
    const float4* src = (const float4*)(&sHf[BUF][q * 32]);                \
    float4 A = src[0], Bv = src[1], C = src[2], D = src[3];                \
    float4 E = src[4], F = src[5], G2 = src[6], H = src[7];                \
    hq[0] = A.x;   hq[1] = A.y;   hq[2] = A.z;   hq[3] = A.w;              \
    hq[4] = Bv.x;  hq[5] = Bv.y;  hq[6] = Bv.z;  hq[7] = Bv.w;             \
    hq[8] = C.x;   hq[9] = C.y;   hq[10] = C.z;  hq[11] = C.w;             \
    hq[12] = D.x;  hq[13] = D.y;  hq[14] = D.z;  hq[15] = D.w;             \
    hq[16] = E.x;  hq[17] = E.y;  hq[18] = E.z;  hq[19] = E.w;             \
    hq[20] = F.x;  hq[21] = F.y;  hq[22] = F.z;  hq[23] = F.w;             \
    hq[24] = G2.x; hq[25] = G2.y; hq[26] = G2.z; hq[27] = G2.w;            \
    hq[28] = H.x;  hq[29] = H.y;  hq[30] = H.z;  hq[31] = H.w;             \
    xc0 = ((const float4*)sXf[NEXT_IDX])[0];                               \
    xc1 = ((const float4*)sXf[NEXT_IDX])[1];                               \
  }

#pragma unroll 1
  for (int ts2 = 0; ts2 < 512; ++ts2) {
    LSTM2_STEP(0, 2 * ts2 + 1)
    LSTM2_STEP(1, 2 * ts2 + 2)
  }
#undef LSTM2_STEP

  // Epilogue: out[b] = (h @ Wd1.T + bd1) @ Wd2.T + bd2; h_T is in sHf[1].
  if (t < 64) {
    float a = bd1[t];
#pragma unroll
    for (int k = 0; k < 128; ++k)
      a = fmaf(Wd1[t * 128 + k], sHf[1][k], a);
    float v = a * Wd2[t];
#pragma unroll
    for (int off = 32; off > 0; off >>= 1) v += __shfl_down(v, off);
    if (t == 0) out[b] = v + bd2[0];
  }
}

extern "C" void kernel_launch(void* const* d_in, const int* in_sizes, int n_in,
                              void* d_out, int out_size, void* d_ws, size_t ws_size,
                              hipStream_t stream) {
  const float* x    = (const float*)d_in[0];
  // d_in[1] is the unused python scalar `data`
  const float* Wih1 = (const float*)d_in[2];
  const float* Whh1 = (const float*)d_in[3];
  const float* bih1 = (const float*)d_in[4];
  const float* bhh1 = (const float*)d_in[5];
  const float* Wih2 = (const float*)d_in[6];
  const float* Whh2 = (const float*)d_in[7];
  const float* bih2 = (const float*)d_in[8];
  const float* bhh2 = (const float*)d_in[9];
  const float* W1   = (const float*)d_in[10];
  const float* b1   = (const float*)d_in[11];
  const float* W2   = (const float*)d_in[12];
  const float* b2   = (const float*)d_in[13];
  float* out = (float*)d_out;

  fused_kernel<<<256, 512, 0, stream>>>(x, Wih1, Whh1, bih1, bhh1,
                                        Wih2, Whh2, bih2, bhh2,
                                        W1, b1, W2, b2, out);
}

// Round 8
// 776.510 us; speedup vs baseline: 1.3921x; 1.0715x over previous
//
#include <hip/hip_runtime.h>
#include <cstdint>

typedef _Float16 f16x2 __attribute__((ext_vector_type(2)));

#define L2E 1.44269504f

// sig2(y) = 1/(1+2^-y)  (y pre-scaled by log2e via weights)
__device__ __forceinline__ float sig2(float y) {
  return __builtin_amdgcn_rcpf(1.f + exp2f(-y));
}
// tanh for runtime (unscaled) cell state c
__device__ __forceinline__ float tanhc(float c) {
  return fmaf(2.f, __builtin_amdgcn_rcpf(1.f + exp2f(c * (-2.f * L2E))), -1.f);
}
__device__ __forceinline__ int packf16(float a, float b) {
  f16x2 p; p.x = (_Float16)a; p.y = (_Float16)b;
  return __builtin_bit_cast(int, p);
}
__device__ __forceinline__ float dot2(int w, int h, float acc) {
  return __builtin_amdgcn_fdot2(__builtin_bit_cast(f16x2, w),
                                __builtin_bit_cast(f16x2, h), acc, false);
}
// Quad-lane permute via DPP (VALU ~4 cyc).
template <int CTRL>
__device__ __forceinline__ float qp(float v) {
  return __int_as_float(__builtin_amdgcn_update_dpp(
      0, __float_as_int(v), CTRL, 0xF, 0xF, true));
}
#define QP_X1 0xB1  // quad_perm [1,0,3,2]  (lane ^ 1)
#define QP_X2 0x4E  // quad_perm [2,3,0,1]  (lane ^ 2)

// ---------------------------------------------------------------------------
// R8 = R7 + two fixes, structure otherwise identical:
//  (1) DE-PARK: launch_bounds(512,1). R7's (512,2) gave 256 unified regs/wave
//      and the allocator split 124 VGPR + ~128 AGPR, parking w[] -> each MAC
//      became ~3 VALU ops (accvgpr shuttles); busy model then predicts
//      VALUBusy 90% vs 91% measured. (512,1) gives a 512-reg budget so the
//      ~200-reg working set fits in arch VGPRs; the 8-wave block still runs
//      2 waves/SIMD physically (latency hiding kept).
//  (2) BANK-CONFLICT rotation: R7's SQ_LDS_BANK_CONFLICT=6.7e7 = 8 reads x
//      4-way x 8 waves x 1024 steps x 256 blocks: the four K-quarters read
//      q*128B-strided segments hitting identical banks. Read segment
//      (j+2q)&7 instead of j (disjoint banks across q), and permute the
//      WEIGHT LOAD identically so the dot product is order-invariant.
//      Offsets precomputed once; all register indices static.
// ---------------------------------------------------------------------------
__global__ __launch_bounds__(512, 1) void fused_kernel(
    const float* __restrict__ x, const float* __restrict__ Wih1,
    const float* __restrict__ Whh1, const float* __restrict__ bih1,
    const float* __restrict__ bhh1, const float* __restrict__ Wih2,
    const float* __restrict__ Whh2, const float* __restrict__ bih2,
    const float* __restrict__ bhh2, const float* __restrict__ Wd1,
    const float* __restrict__ bd1, const float* __restrict__ Wd2,
    const float* __restrict__ bd2, float* __restrict__ out) {
  __shared__ __align__(16) float sXf[1026][8];   // h1 sequence, f32 (32.8 KB)
  __shared__ __align__(16) float sHf[2][128];    // double-buffered h, f32

  const int b = blockIdx.x;
  const int t = threadIdx.x;

  // ======================== Phase 1: lstm1 (dot2) ========================
  {
    int whh2[128];
#pragma unroll
    for (int r = 0; r < 32; ++r) {
      const float s = (r >> 3) == 2 ? 2.f * L2E : L2E;
#pragma unroll
      for (int j = 0; j < 4; ++j) {
        float2 v = ((const float2*)(Whh1 + r * 8))[j];
        whh2[r * 4 + j] = packf16(v.x * s, v.y * s);
      }
    }
    int wxb[32];
#pragma unroll
    for (int r = 0; r < 32; ++r) {
      const float s = (r >> 3) == 2 ? 2.f * L2E : L2E;
      wxb[r] = packf16(Wih1[r] * s, (bih1[r] + bhh1[r]) * s);
    }
#pragma unroll
    for (int i = 0; i < 128; i += 8)
      asm volatile("" : "+v"(whh2[i]), "+v"(whh2[i + 1]), "+v"(whh2[i + 2]),
                        "+v"(whh2[i + 3]), "+v"(whh2[i + 4]), "+v"(whh2[i + 5]),
                        "+v"(whh2[i + 6]), "+v"(whh2[i + 7]));

#pragma unroll 1
    for (int ch = 0; ch < 2; ++ch) {
      const int c = ch * 512 + t;  // chain index within this batch row
      const float* __restrict__ xp = x + ((size_t)b * 1024 + c) * 16;
      float cc[8];
      int h2[4];
#pragma unroll
      for (int k = 0; k < 8; ++k) cc[k] = 0.f;
#pragma unroll
      for (int j = 0; j < 4; ++j) h2[j] = 0;

      float hn[8];
      float xv = xp[0];
#pragma unroll 1
      for (int u = 0; u < 16; ++u) {
        float xnl = xp[(u + 1) & 15];  // 1-ahead prefetch (same line)
        const int xt1 = packf16(xv, 1.f);
#pragma unroll
        for (int k = 0; k < 8; ++k) {
          float acc[4];
#pragma unroll
          for (int gi = 0; gi < 4; ++gi) {
            const int r = gi * 8 + k;
            float a = dot2(wxb[r], xt1, 0.f);
            a = dot2(whh2[r * 4 + 0], h2[0], a);
            a = dot2(whh2[r * 4 + 1], h2[1], a);
            a = dot2(whh2[r * 4 + 2], h2[2], a);
            a = dot2(whh2[r * 4 + 3], h2[3], a);
            acc[gi] = a;
          }
          float iv = sig2(acc[0]), fv = sig2(acc[1]);
          float gv = fmaf(2.f, sig2(acc[2]), -1.f), ov = sig2(acc[3]);
          cc[k] = fmaf(fv, cc[k], iv * gv);
          hn[k] = ov * tanhc(cc[k]);
        }
#pragma unroll
        for (int j = 0; j < 4; ++j) h2[j] = packf16(hn[2 * j], hn[2 * j + 1]);
        xv = xnl;
      }
      // store final h as f32 directly (2 x ds_write_b128)
      float4* dst = (float4*)sXf[c];
      float4 o0v, o1v;
      o0v.x = hn[0]; o0v.y = hn[1]; o0v.z = hn[2]; o0v.w = hn[3];
      o1v.x = hn[4]; o1v.y = hn[5]; o1v.z = hn[6]; o1v.w = hn[7];
      dst[0] = o0v; dst[1] = o1v;
    }
  }

  // ======================== Phase 2: lstm2 (f32 fma) ========================
  const int m = t >> 2;  // hidden index (0..127)
  const int q = t & 3;   // K-quarter = DPP quad lane
  const int G = ((q & 1) << 1) | (q >> 1);  // gate this thread finalizes
  const bool sel0 = (q & 1) != 0;
  const bool sel1 = (q & 2) != 0;
  const bool isq0 = (q == 0);
  const bool isq1 = (q == 1);  // G==2 (tanh gate)

  // Rotated float4-segment indices within sHf (conflict-free across q):
  // segment for slot j is (j + 2q) & 7; o_j = q*8 + that (float4 units).
  const int o0 = q * 8 + ((0 + 2 * q) & 7);
  const int o1 = q * 8 + ((1 + 2 * q) & 7);
  const int o2 = q * 8 + ((2 + 2 * q) & 7);
  const int o3 = q * 8 + ((3 + 2 * q) & 7);
  const int o4 = q * 8 + ((4 + 2 * q) & 7);
  const int o5 = q * 8 + ((5 + 2 * q) & 7);
  const int o6 = q * 8 + ((6 + 2 * q) & 7);
  const int o7 = q * 8 + ((7 + 2 * q) & 7);

  // K-quarter q of all four gate rows of index m, f32, log2e-folded per
  // gate, loaded in the SAME rotated segment order as the sHf reads.
  float w[128];
#pragma unroll
  for (int g = 0; g < 4; ++g) {
    const float s = (g == 2) ? 2.f * L2E : L2E;
    const float4* p = (const float4*)(Whh2 + (size_t)(g * 128 + m) * 128 + q * 32);
#pragma unroll
    for (int j = 0; j < 8; ++j) {
      const int jr = (j + 2 * q) & 7;  // runtime addr, static reg slots
      float4 v = p[jr];
      w[g * 32 + 4 * j + 0] = v.x * s;
      w[g * 32 + 4 * j + 1] = v.y * s;
      w[g * 32 + 4 * j + 2] = v.z * s;
      w[g * 32 + 4 * j + 3] = v.w * s;
    }
  }
#pragma unroll
  for (int i = 0; i < 128; i += 8)
    asm volatile("" : "+v"(w[i]), "+v"(w[i + 1]), "+v"(w[i + 2]),
                      "+v"(w[i + 3]), "+v"(w[i + 4]), "+v"(w[i + 5]),
                      "+v"(w[i + 6]), "+v"(w[i + 7]));

  // x row + bias for the gate this thread finalizes (row G*128+m), f32.
  float wig[8];
  float bias;
  {
    const float s = (G == 2) ? 2.f * L2E : L2E;
    const float4* pi = (const float4*)(Wih2 + (size_t)(G * 128 + m) * 8);
    float4 a = pi[0], bv = pi[1];
    wig[0] = a.x * s;  wig[1] = a.y * s;  wig[2] = a.z * s;  wig[3] = a.w * s;
    wig[4] = bv.x * s; wig[5] = bv.y * s; wig[6] = bv.z * s; wig[7] = bv.w * s;
    bias = (bih2[G * 128 + m] + bhh2[G * 128 + m]) * s;
  }

  float hq[32];  // this thread's h-quarter (32 f32), rotated-segment order
#pragma unroll
  for (int i = 0; i < 32; ++i) hq[i] = 0.f;
  float c = 0.f;

  __syncthreads();  // sXf fully written
  float4 xc0 = ((const float4*)sXf[0])[0];
  float4 xc1 = ((const float4*)sXf[0])[1];

#define LSTM2_STEP(BUF, NEXT_IDX)                                          \
  {                                                                        \
    float bx = bias;                                                       \
    bx = fmaf(wig[0], xc0.x, bx);                                          \
    bx = fmaf(wig[1], xc0.y, bx);                                          \
    bx = fmaf(wig[2], xc0.z, bx);                                          \
    bx = fmaf(wig[3], xc0.w, bx);                                          \
    bx = fmaf(wig[4], xc1.x, bx);                                          \
    bx = fmaf(wig[5], xc1.y, bx);                                          \
    bx = fmaf(wig[6], xc1.z, bx);                                          \
    bx = fmaf(wig[7], xc1.w, bx);                                          \
    float R0a = 0.f, R1a = 0.f, R2a = 0.f, R3a = 0.f;                      \
    float R0b = 0.f, R1b = 0.f, R2b = 0.f, R3b = 0.f;                      \
    _Pragma("unroll")                                                      \
    for (int j = 0; j < 16; ++j) {                                         \
      R0a = fmaf(w[j], hq[j], R0a);                                        \
      R1a = fmaf(w[32 + j], hq[j], R1a);                                   \
      R2a = fmaf(w[64 + j], hq[j], R2a);                                   \
      R3a = fmaf(w[96 + j], hq[j], R3a);                                   \
    }                                                                      \
    _Pragma("unroll")                                                      \
    for (int j = 16; j < 32; ++j) {                                        \
      R0b = fmaf(w[j], hq[j], R0b);                                        \
      R1b = fmaf(w[32 + j], hq[j], R1b);                                   \
      R2b = fmaf(w[64 + j], hq[j], R2b);                                   \
      R3b = fmaf(w[96 + j], hq[j], R3b);                                   \
    }                                                                      \
    float R0 = R0a + R0b, R1 = R1a + R1b;                                  \
    float R2 = R2a + R2b, R3 = R3a + R3b;                                  \
    float s0 = sel0 ? R0 : R2, s1 = sel0 ? R1 : R3;                        \
    float k0 = sel0 ? R2 : R0, k1 = sel0 ? R3 : R1;                        \
    float S0 = k0 + qp<QP_X1>(s0);                                         \
    float S1 = k1 + qp<QP_X1>(s1);                                         \
    float s2 = sel1 ? S0 : S1;                                             \
    float k2 = sel1 ? S1 : S0;                                             \
    float S = k2 + qp<QP_X2>(s2) + bx;                                     \
    float sg = sig2(S);                                                    \
    float act = isq1 ? fmaf(2.f, sg, -1.f) : sg;                           \
    float v0 = act;                                                        \
    float v1 = qp<QP_X1>(v0);                                              \
    float v2 = qp<QP_X2>(v0);                                              \
    float v3 = qp<QP_X2>(v1);                                              \
    float p01 = sel0 ? v1 : v0, p23 = sel0 ? v3 : v2;                      \
    float q01 = sel0 ? v0 : v1, q23 = sel0 ? v2 : v3;                      \
    float iv = sel1 ? p23 : p01;                                           \
    float fv = sel1 ? p01 : p23;                                           \
    float gv = sel1 ? q23 : q01;                                           \
    float ov = sel1 ? q01 : q23;                                           \
    c = fmaf(fv, c, iv * gv);                                              \
    float hx = ov * tanhc(c);                                              \
    if (isq0) sHf[BUF][m] = hx;                                            \
    __syncthreads();                                                       \
    const float4* srcB = (const float4*)(sHf[BUF]);                        \
    float4 A = srcB[o0], Bv = srcB[o1], C = srcB[o2], D = srcB[o3];        \
    float4 E = srcB[o4], F = srcB[o5], G2 = srcB[o6], H = srcB[o7];        \
    hq[0] = A.x;   hq[1] = A.y;   hq[2] = A.z;   hq[3] = A.w;              \
    hq[4] = Bv.x;  hq[5] = Bv.y;  hq[6] = Bv.z;  hq[7] = Bv.w;             \
    hq[8] = C.x;   hq[9] = C.y;   hq[10] = C.z;  hq[11] = C.w;             \
    hq[12] = D.x;  hq[13] = D.y;  hq[14] = D.z;  hq[15] = D.w;             \
    hq[16] = E.x;  hq[17] = E.y;  hq[18] = E.z;  hq[19] = E.w;             \
    hq[20] = F.x;  hq[21] = F.y;  hq[22] = F.z;  hq[23] = F.w;             \
    hq[24] = G2.x; hq[25] = G2.y; hq[26] = G2.z; hq[27] = G2.w;            \
    hq[28] = H.x;  hq[29] = H.y;  hq[30] = H.z;  hq[31] = H.w;             \
    xc0 = ((const float4*)sXf[NEXT_IDX])[0];                               \
    xc1 = ((const float4*)sXf[NEXT_IDX])[1];                               \
  }

#pragma unroll 1
  for (int ts2 = 0; ts2 < 512; ++ts2) {
    LSTM2_STEP(0, 2 * ts2 + 1)
    LSTM2_STEP(1, 2 * ts2 + 2)
  }
#undef LSTM2_STEP

  // Epilogue: out[b] = (h @ Wd1.T + bd1) @ Wd2.T + bd2; h_T is in sHf[1].
  if (t < 64) {
    float a = bd1[t];
#pragma unroll
    for (int k = 0; k < 128; ++k)
      a = fmaf(Wd1[t * 128 + k], sHf[1][k], a);
    float v = a * Wd2[t];
#pragma unroll
    for (int off = 32; off > 0; off >>= 1) v += __shfl_down(v, off);
    if (t == 0) out[b] = v + bd2[0];
  }
}

extern "C" void kernel_launch(void* const* d_in, const int* in_sizes, int n_in,
                              void* d_out, int out_size, void* d_ws, size_t ws_size,
                              hipStream_t stream) {
  const float* x    = (const float*)d_in[0];
  // d_in[1] is the unused python scalar `data`
  const float* Wih1 = (const float*)d_in[2];
  const float* Whh1 = (const float*)d_in[3];
  const float* bih1 = (const float*)d_in[4];
  const float* bhh1 = (const float*)d_in[5];
  const float* Wih2 = (const float*)d_in[6];
  const float* Whh2 = (const float*)d_in[7];
  const float* bih2 = (const float*)d_in[8];
  const float* bhh2 = (const float*)d_in[9];
  const float* W1   = (const float*)d_in[10];
  const float* b1   = (const float*)d_in[11];
  const float* W2   = (const float*)d_in[12];
  const float* b2   = (const float*)d_in[13];
  float* out = (float*)d_out;

  fused_kernel<<<256, 512, 0, stream>>>(x, Wih1, Whh1, bih1, bhh1,
                                        Wih2, Whh2, bih2, bhh2,
                                        W1, b1, W2, b2, out);
}